// Round 4
// baseline (329.017 us; speedup 1.0000x reference)
//
#include <hip/hip_runtime.h>
#include <hip/hip_bf16.h>

typedef short short8 __attribute__((ext_vector_type(8)));
typedef short short4v __attribute__((ext_vector_type(4)));
typedef float floatx4 __attribute__((ext_vector_type(4)));

constexpr int BATCH = 4;
constexpr int SEQ = 2048;
constexpr int DMODEL = 1024;
constexpr int NHEADS = 16;
constexpr int DKH = 64;
constexpr int MROWS = BATCH * SEQ;             // 8192
constexpr size_t NE = (size_t)MROWS * DMODEL;  // 8388608 elements
constexpr size_t WE = (size_t)DMODEL * DMODEL; // 1048576 elements
constexpr float SC = 0.18033688011112042f;     // (1/8) * log2(e), folded into Wq

__device__ __forceinline__ short f2bf(float f) {
    unsigned u = __float_as_uint(f);
    u += 0x7fffu + ((u >> 16) & 1u);
    return (short)(u >> 16);
}

__device__ __forceinline__ short2 pk2(float a, float b) {
    __hip_bfloat162 h = __float22bfloat162_rn(float2{a, b});
    short2 r;
    __builtin_memcpy(&r, &h, 4);
    return r;
}

// async 16B global -> LDS (lds dst is wave-uniform; HW adds lane*16)
__device__ __forceinline__ void ld16(const void* g, void* l) {
    __builtin_amdgcn_global_load_lds(
        (const __attribute__((address_space(1))) unsigned int*)g,
        (__attribute__((address_space(3))) unsigned int*)l, 16, 0, 0);
}

// counted-vmcnt sync points (T4): sched_barrier pins both sides so no
// LDS read can hoist above the barrier and no stage can sink below its
// phase (rules #18/#21). vmcnt counted so prefetch loads stay in flight.
__device__ __forceinline__ void sync_vm3() {
    asm volatile("s_waitcnt vmcnt(3)" ::: "memory");
    __builtin_amdgcn_sched_barrier(0);
    __builtin_amdgcn_s_barrier();
    __builtin_amdgcn_sched_barrier(0);
}
__device__ __forceinline__ void sync_vm0() {
    asm volatile("s_waitcnt vmcnt(0)" ::: "memory");
    __builtin_amdgcn_sched_barrier(0);
    __builtin_amdgcn_s_barrier();
    __builtin_amdgcn_sched_barrier(0);
}

__global__ __launch_bounds__(256) void f32_to_bf16(const float* __restrict__ s,
                                                   short* __restrict__ d, int n4) {
    int i = blockIdx.x * blockDim.x + threadIdx.x;
    const int stride = gridDim.x * blockDim.x;
    for (; i < n4; i += stride) {
        float4 f = ((const float4*)s)[i];
        short4v v;
        v[0] = f2bf(f.x); v[1] = f2bf(f.y); v[2] = f2bf(f.z); v[3] = f2bf(f.w);
        ((short4v*)d)[i] = v;
    }
}

// convert two equal-size fp32 arrays -> bf16 in one launch (y selects)
__global__ __launch_bounds__(256) void cvt2(const float* __restrict__ s0,
                                            const float* __restrict__ s1,
                                            short* __restrict__ d0,
                                            short* __restrict__ d1, int n4) {
    const float* s = blockIdx.y ? s1 : s0;
    short* d = blockIdx.y ? d1 : d0;
    int i = blockIdx.x * blockDim.x + threadIdx.x;
    const int stride = gridDim.x * blockDim.x;
    for (; i < n4; i += stride) {
        float4 f = ((const float4*)s)[i];
        short4v v;
        v[0] = f2bf(f.x); v[1] = f2bf(f.y); v[2] = f2bf(f.z); v[3] = f2bf(f.w);
        ((short4v*)d)[i] = v;
    }
}

// convert three weight matrices -> bf16; y==0 (Wq) pre-scaled by SC so the
// Q projection GEMM needs no epilogue scale.
__global__ __launch_bounds__(256) void wcvt3(const float* __restrict__ a,
                                             const float* __restrict__ b,
                                             const float* __restrict__ c,
                                             short* __restrict__ dst, int n4) {
    const float* s = (blockIdx.y == 0) ? a : (blockIdx.y == 1) ? b : c;
    const float m = (blockIdx.y == 0) ? SC : 1.0f;
    short* d = dst + (size_t)blockIdx.y * (size_t)n4 * 4;
    int i = blockIdx.x * blockDim.x + threadIdx.x;
    const int stride = gridDim.x * blockDim.x;
    for (; i < n4; i += stride) {
        float4 f = ((const float4*)s)[i];
        short4v v;
        v[0] = f2bf(f.x * m); v[1] = f2bf(f.y * m);
        v[2] = f2bf(f.z * m); v[3] = f2bf(f.w * m);
        ((short4v*)d)[i] = v;
    }
}

// One compute phase: K-half KS of the current BK=64 tile. Each of 8 waves
// (4M x 2N) reads 4 A-frags + 4 B-frags (ds_read_b128, swizzled) and does
// 16 MFMA wrapped in setprio (T5).
template <int KS>
__device__ __forceinline__ void do_phase(const short* Ab, const short* Bb,
                                         floatx4 (&acc)[4][4], int wm, int wn,
                                         int lane16, int quad, int fsw) {
    short8 af[4], bf[4];
#pragma unroll
    for (int i = 0; i < 4; ++i)
        af[i] = *(const short8*)&Ab[KS * (256 * 32) + (wm + i * 16 + lane16) * 32 +
                                    ((quad ^ fsw) * 8)];
#pragma unroll
    for (int j = 0; j < 4; ++j)
        bf[j] = *(const short8*)&Bb[KS * (128 * 32) + (wn + j * 16 + lane16) * 32 +
                                    ((quad ^ fsw) * 8)];
    __builtin_amdgcn_s_setprio(1);
#pragma unroll
    for (int i = 0; i < 4; ++i)
#pragma unroll
        for (int j = 0; j < 4; ++j)
            acc[i][j] = __builtin_amdgcn_mfma_f32_16x16x32_bf16(af[i], bf[j],
                                                                acc[i][j], 0, 0, 0);
    __builtin_amdgcn_s_setprio(0);
}

// Y[m][n] = sum_k A[m][k] * B[n][k]  (NT GEMM, M=8192, N=K=1024). A,B bf16.
// BM=256 x BN=128 tile, BK=64, 512 threads = 8 waves (4M x 2N), per-wave
// 64x64 output. Full-chip geometry: grid (32, 8) = 256 blocks = 1/CU
// (round-3's BN=256 left half the CUs idle on N=1024).
// Counted-vmcnt schedule (T3+T4): per K-tile, 2 phases, each staging 3
// 16B-per-thread units of tile t+1 (2xA + 1xB global_load_lds) while
// computing 16 MFMA; syncs use s_waitcnt vmcnt(3) -- never drained to 0
// in the main loop. LDS 96 KiB double-buffered. XOR-chunk swizzle with key
// (row>>1)&3 pre-applied to the per-lane GLOBAL address (global_load_lds
// lands linearly); fragment reads de-swizzle with fsw=(lane16>>1)&3.
// OUT_MODE 0: bf16 row-major; 1: bf16 V-transposed [(b*16+h)*64+d][s];
// 2: fp32 row-major (final output).
template <int OUT_MODE>
__device__ __forceinline__ void gemm_body(const short* A, const short* B,
                                          void* Yp) {
    __shared__ __align__(16) short Asw[2][2][256 * 32]; // [buf][ks][row*32+ch]
    __shared__ __align__(16) short Bsw[2][2][128 * 32];

    const int tid = threadIdx.x;
    const int w = tid >> 6, l = tid & 63;
    const int lane16 = l & 15, quad = l >> 4;
    const int wm = (w >> 1) * 64, wn = (w & 1) * 64;
    const int m0 = blockIdx.x * 256, n0 = blockIdx.y * 128;
    const int fsw = (lane16 >> 1) & 3; // fragment-read swizzle key

    // staging ownership: thread -> row rr (and rr+128 for A), 16B chunk cc,
    // pre-swizzled on the global side. Key (rr>>1)&3 == ((rr+128)>>1)&3.
    const int rr = tid >> 2;                    // 0..127
    const int cc = (tid & 3) ^ ((rr >> 1) & 3); // swizzled global chunk
    const int ldsW0 = (w * 16) * 32;            // wave's linear landing (shorts)
    const int ldsW1 = (128 + w * 16) * 32;

    auto stA = [&](int k0, int bufi, int ks) {
        const short* g = A + (size_t)(m0 + rr) * DMODEL + k0 + ks * 32 + cc * 8;
        ld16(g, &Asw[bufi][ks][ldsW0]);
        ld16(g + (size_t)128 * DMODEL, &Asw[bufi][ks][ldsW1]);
    };
    auto stB = [&](int k0, int bufi, int ks) {
        const short* g = B + (size_t)(n0 + rr) * DMODEL + k0 + ks * 32 + cc * 8;
        ld16(g, &Bsw[bufi][ks][ldsW0]);
    };

    floatx4 acc[4][4];
#pragma unroll
    for (int i = 0; i < 4; ++i)
#pragma unroll
        for (int j = 0; j < 4; ++j) acc[i][j] = {0.f, 0.f, 0.f, 0.f};

    constexpr int NT = DMODEL / 64; // 16 K-tiles
    // prologue: both K-halves of tile 0 (6 loads); wait for ks0 (first 3),
    // leave ks1 in flight.
    stA(0, 0, 0); stB(0, 0, 0);
    stA(0, 0, 1); stB(0, 0, 1);
    sync_vm3();

    for (int t = 0; t < NT; ++t) {
        const int cur = t & 1, nxt = cur ^ 1;
        const short* Ab = &Asw[cur][0][0];
        const short* Bb = &Bsw[cur][0][0];
        const int k1 = (t + 1) * 64;
        const bool more = (t + 1 < NT);

        // P0: stage ks0(t+1); compute ks0(t)
        if (more) { stA(k1, nxt, 0); stB(k1, nxt, 0); }
        do_phase<0>(Ab, Bb, acc, wm, wn, lane16, quad, fsw);
        // mid sync: ks1(t) landed; ks0(t+1) stays in flight
        if (more) sync_vm3(); else sync_vm0();
        // P1: stage ks1(t+1); compute ks1(t)
        if (more) { stA(k1, nxt, 1); stB(k1, nxt, 1); }
        do_phase<1>(Ab, Bb, acc, wm, wn, lane16, quad, fsw);
        // end sync: ks0(t+1) landed; ks1(t+1) stays in flight
        if (more) sync_vm3();
    }

    const int gmb = m0 + wm, gnb = n0 + wn;
    if (OUT_MODE == 0) {
        short* Y = (short*)Yp;
#pragma unroll
        for (int mi = 0; mi < 4; ++mi)
#pragma unroll
            for (int ni = 0; ni < 4; ++ni) {
                const int gm = gmb + mi * 16 + quad * 4;
                const int gn = gnb + ni * 16 + lane16;
#pragma unroll
                for (int r = 0; r < 4; ++r)
                    Y[(size_t)(gm + r) * DMODEL + gn] = f2bf(acc[mi][ni][r]);
            }
    } else if (OUT_MODE == 1) {
        short* Y = (short*)Yp;
#pragma unroll
        for (int mi = 0; mi < 4; ++mi)
#pragma unroll
            for (int ni = 0; ni < 4; ++ni) {
                const int gm = gmb + mi * 16 + quad * 4;
                const int gn = gnb + ni * 16 + lane16;
                const int bb = gm >> 11, ss = gm & (SEQ - 1);
                const int hh = gn >> 6, dd = gn & 63;
                const size_t base = ((size_t)(bb * NHEADS + hh) * DKH + dd) * SEQ + ss;
                short4v vv;
#pragma unroll
                for (int r = 0; r < 4; ++r) vv[r] = f2bf(acc[mi][ni][r]);
                *(short4v*)(Y + base) = vv;
            }
    } else {
        float* Y = (float*)Yp;
#pragma unroll
        for (int mi = 0; mi < 4; ++mi)
#pragma unroll
            for (int ni = 0; ni < 4; ++ni) {
                const int gm = gmb + mi * 16 + quad * 4;
                const int gn = gnb + ni * 16 + lane16;
#pragma unroll
                for (int r = 0; r < 4; ++r)
                    Y[(size_t)(gm + r) * DMODEL + gn] = acc[mi][ni][r];
            }
    }
}

template <int OUT_MODE>
__global__ __launch_bounds__(512, 2) void gemm_nt(const short* __restrict__ A,
                                                  const short* __restrict__ B,
                                                  void* __restrict__ Yp) {
    gemm_body<OUT_MODE>(A, B, Yp);
}

// Q and K projections batched in one launch: grid (32, 8, 2), z selects.
// 512 blocks = two full-chip passes at 1 block/CU.
__global__ __launch_bounds__(512, 2) void gemm_qk(const short* __restrict__ Aq,
                                                  const short* __restrict__ Ak,
                                                  const short* __restrict__ Wqk,
                                                  short* __restrict__ Yq,
                                                  short* __restrict__ Yk) {
    const int z = blockIdx.z;
    gemm_body<0>(z ? Ak : Aq, Wqk + (size_t)z * WE, z ? Yk : Yq);
}

// Flash attention, causal, S^T form, no max-subtraction. (unchanged)
__global__ __launch_bounds__(256, 4) void attn_fwd(const short* __restrict__ Qb,
                                                   const short* __restrict__ Kb,
                                                   const short* __restrict__ Vt,
                                                   short* __restrict__ Oc) {
    __shared__ __align__(16) short Kl[2][64 * 64];
    __shared__ __align__(16) short Vl[2][64 * 64];
    __shared__ __align__(16) short Plds[4][16][64]; // per-wave P transpose, XOR-swizzled

    const int bh = blockIdx.x;                        // XCD = bh % 8
    const int qt = (int)(gridDim.y - 1) - blockIdx.y; // longest blocks first
    const int b = bh >> 4, h = bh & 15;
    const int tid = threadIdx.x;
    const int w = tid >> 6, l = tid & 63;
    const int lane16 = l & 15, quad = l >> 4;

    const short* Qrow =
        Qb + ((size_t)b * SEQ + qt * 64 + w * 16 + lane16) * DMODEL + h * DKH;
    const short8 qf0 = *(const short8*)(Qrow + quad * 8);
    const short8 qf1 = *(const short8*)(Qrow + 32 + quad * 8);

    const int r0 = tid >> 3, c0 = tid & 7;
    const int sc0 = c0 ^ (r0 & 7);
    const short* Kg = Kb + (size_t)b * SEQ * DMODEL + h * DKH; // K[s][d]
    const short* Vg = Vt + (size_t)bh * DKH * SEQ;             // V^T[d][s]

    short8 kra, krb, vra, vrb;
    kra = *(const short8*)(Kg + (size_t)r0 * DMODEL + c0 * 8);
    krb = *(const short8*)(Kg + (size_t)(r0 + 32) * DMODEL + c0 * 8);
    vra = *(const short8*)(Vg + (size_t)r0 * SEQ + c0 * 8);
    vrb = *(const short8*)(Vg + (size_t)(r0 + 32) * SEQ + c0 * 8);
    *(short8*)&Kl[0][r0 * 64 + sc0 * 8] = kra;
    *(short8*)&Kl[0][(r0 + 32) * 64 + sc0 * 8] = krb;
    *(short8*)&Vl[0][r0 * 64 + sc0 * 8] = vra;
    *(short8*)&Vl[0][(r0 + 32) * 64 + sc0 * 8] = vrb;
    if (qt > 0) {
        kra = *(const short8*)(Kg + (size_t)(64 + r0) * DMODEL + c0 * 8);
        krb = *(const short8*)(Kg + (size_t)(64 + r0 + 32) * DMODEL + c0 * 8);
        vra = *(const short8*)(Vg + (size_t)r0 * SEQ + 64 + c0 * 8);
        vrb = *(const short8*)(Vg + (size_t)(r0 + 32) * SEQ + 64 + c0 * 8);
    }

    floatx4 oacc[4];
#pragma unroll
    for (int ni = 0; ni < 4; ++ni) oacc[ni] = {0.f, 0.f, 0.f, 0.f};
    float Lp = 0.f;
    const int swz = lane16 & 7;
    const int psw = lane16 & 7;

    for (int kt = 0; kt <= qt; ++kt) {
        const int cur = kt & 1;
        __syncthreads();
        if (kt < qt) {
            const int nb = cur ^ 1;
            *(short8*)&Kl[nb][r0 * 64 + sc0 * 8] = kra;
            *(short8*)&Kl[nb][(r0 + 32) * 64 + sc0 * 8] = krb;
            *(short8*)&Vl[nb][r0 * 64 + sc0 * 8] = vra;
            *(short8*)&Vl[nb][(r0 + 32) * 64 + sc0 * 8] = vrb;
            if (kt + 1 < qt) {
                const int kn = (kt + 2) * 64;
                kra = *(const short8*)(Kg + (size_t)(kn + r0) * DMODEL + c0 * 8);
                krb = *(const short8*)(Kg + (size_t)(kn + r0 + 32) * DMODEL + c0 * 8);
                vra = *(const short8*)(Vg + (size_t)r0 * SEQ + kn + c0 * 8);
                vrb = *(const short8*)(Vg + (size_t)(r0 + 32) * SEQ + kn + c0 * 8);
            }
        }

        float p[4][4];
#pragma unroll
        for (int nt = 0; nt < 4; ++nt) {
            const short* kr = &Kl[cur][(nt * 16 + lane16) * 64];
            floatx4 st = {0.f, 0.f, 0.f, 0.f};
            st = __builtin_amdgcn_mfma_f32_16x16x32_bf16(
                *(const short8*)(kr + (quad ^ swz) * 8), qf0, st, 0, 0, 0);
            st = __builtin_amdgcn_mfma_f32_16x16x32_bf16(
                *(const short8*)(kr + ((4 + quad) ^ swz) * 8), qf1, st, 0, 0, 0);
#pragma unroll
            for (int r = 0; r < 4; ++r) p[nt][r] = st[r];
        }

#pragma unroll
        for (int nt = 0; nt < 4; ++nt)
#pragma unroll
            for (int r = 0; r < 4; ++r) p[nt][r] = __builtin_amdgcn_exp2f(p[nt][r]);

        if (kt == qt) {
            const int qloc = w * 16 + lane16;
#pragma unroll
            for (int nt = 0; nt < 4; ++nt)
#pragma unroll
                for (int r = 0; r < 4; ++r)
                    if (nt * 16 + quad * 4 + r > qloc) p[nt][r] = 0.f;
        }

        float rs01 = 0.f, rs23 = 0.f;
#pragma unroll
        for (int nt = 0; nt < 4; ++nt)
#pragma unroll
            for (int r = 0; r < 4; ++r) {
                if (nt < 2) rs01 += p[nt][r]; else rs23 += p[nt][r];
            }
        Lp += rs01 + rs23;

#pragma unroll
        for (int nt = 0; nt < 4; ++nt) {
            const short2 lo = pk2(p[nt][0], p[nt][1]);
            const short2 hi = pk2(p[nt][2], p[nt][3]);
            short4v pk;
            pk[0] = lo.x; pk[1] = lo.y; pk[2] = hi.x; pk[3] = hi.y;
            const int pch = (nt * 2 + (quad >> 1)) ^ psw;
            *(short4v*)&Plds[w][lane16][pch * 8 + (quad & 1) * 4] = pk;
        }
        const short8 pf0 = *(const short8*)&Plds[w][lane16][(quad ^ psw) * 8];
        const short8 pf1 = *(const short8*)&Plds[w][lane16][((4 + quad) ^ psw) * 8];

#pragma unroll
        for (int ni = 0; ni < 4; ++ni) {
            const short* vr = &Vl[cur][(ni * 16 + lane16) * 64];
            oacc[ni] = __builtin_amdgcn_mfma_f32_16x16x32_bf16(
                pf0, *(const short8*)(vr + (quad ^ swz) * 8), oacc[ni], 0, 0, 0);
            oacc[ni] = __builtin_amdgcn_mfma_f32_16x16x32_bf16(
                pf1, *(const short8*)(vr + ((4 + quad) ^ swz) * 8), oacc[ni], 0, 0, 0);
        }
    }

    float L = Lp + __shfl_xor(Lp, 16);
    L += __shfl_xor(L, 32);
    float linv[4];
#pragma unroll
    for (int r = 0; r < 4; ++r) linv[r] = 1.f / __shfl(L, quad * 4 + r);
#pragma unroll
    for (int r = 0; r < 4; ++r) {
        const int qg = qt * 64 + w * 16 + quad * 4 + r;
#pragma unroll
        for (int ni = 0; ni < 4; ++ni)
            Oc[((size_t)b * SEQ + qg) * DMODEL + h * DKH + ni * 16 + lane16] =
                f2bf(oacc[ni][r] * linv[r]);
    }
}

extern "C" void kernel_launch(void* const* d_in, const int* in_sizes, int n_in,
                              void* d_out, int out_size, void* d_ws, size_t ws_size,
                              hipStream_t stream) {
    const float* q = (const float*)d_in[0];
    const float* k = (const float*)d_in[1];
    const float* v = (const float*)d_in[2];
    const float* Wq = (const float*)d_in[3];
    const float* Wk = (const float*)d_in[4];
    const float* Wv = (const float*)d_in[5];
    const float* Wo = (const float*)d_in[6];

    short* Qb = (short*)d_ws;     // ws: exactly 4*NE bf16 = 67.1 MB
    short* Kb = Qb + NE;
    short* Vt = Kb + NE;
    short* Cc = Vt + NE;
    // scratch inside d_out (33.5 MB fp32, dead until the final GEMM):
    short* Wqb = (short*)d_out;   // [0, 3*WE): bf16 Wq (SC-scaled) / Wk / Wv
    short* Wkb = Wqb + WE;
    short* Wvb = Wqb + 2 * WE;
    short* Kbf = Wqb + 3 * WE;    // [3*WE, 3*WE+NE): bf16 key activation
    short* Wob = Vt;              // Vt dead after attn

    dim3 gg(MROWS / 256, DMODEL / 128);     // (32, 8): 256 blocks = 1/CU
    dim3 gqk(MROWS / 256, DMODEL / 128, 2); // (32, 8, 2): 512 blocks
    dim3 ga(BATCH * NHEADS, SEQ / 64);      // (64, 32): x = bh -> XCD affinity
    const int actN4 = (int)(NE / 4), wN4 = (int)(WE / 4);

    wcvt3<<<dim3(256, 3), 256, 0, stream>>>(Wq, Wk, Wv, (short*)d_out, wN4);
    cvt2<<<dim3(1024, 2), 256, 0, stream>>>(q, k, Cc, Kbf, actN4);
    gemm_qk<<<gqk, 512, 0, stream>>>(Cc, Kbf, Wqb, Qb, Kb);
    f32_to_bf16<<<2048, 256, 0, stream>>>(v, Cc, actN4);
    gemm_nt<1><<<gg, 512, 0, stream>>>(Cc, Wvb, Vt);
    attn_fwd<<<ga, 256, 0, stream>>>(Qb, Kb, Vt, Cc);
    f32_to_bf16<<<512, 256, 0, stream>>>(Wo, Wob, wN4);
    gemm_nt<2><<<gg, 512, 0, stream>>>(Cc, Wob, d_out);
}

// Round 5
// 321.535 us; speedup vs baseline: 1.0233x; 1.0233x over previous
//
#include <hip/hip_runtime.h>
#include <hip/hip_bf16.h>

typedef short short8 __attribute__((ext_vector_type(8)));
typedef short short4v __attribute__((ext_vector_type(4)));
typedef float floatx4 __attribute__((ext_vector_type(4)));

constexpr int BATCH = 4;
constexpr int SEQ = 2048;
constexpr int DMODEL = 1024;
constexpr int NHEADS = 16;
constexpr int DKH = 64;
constexpr int MROWS = BATCH * SEQ;             // 8192
constexpr size_t NE = (size_t)MROWS * DMODEL;  // 8388608 elements
constexpr size_t WE = (size_t)DMODEL * DMODEL; // 1048576 elements
constexpr float SC = 0.18033688011112042f;     // (1/8) * log2(e), folded into Wq

__device__ __forceinline__ short f2bf(float f) {
    unsigned u = __float_as_uint(f);
    u += 0x7fffu + ((u >> 16) & 1u);
    return (short)(u >> 16);
}

__device__ __forceinline__ short2 pk2(float a, float b) {
    __hip_bfloat162 h = __float22bfloat162_rn(float2{a, b});
    short2 r;
    __builtin_memcpy(&r, &h, 4);
    return r;
}

// async 16B global -> LDS (lds dst is wave-uniform; HW adds lane*16)
__device__ __forceinline__ void ld16(const void* g, void* l) {
    __builtin_amdgcn_global_load_lds(
        (const __attribute__((address_space(1))) unsigned int*)g,
        (__attribute__((address_space(3))) unsigned int*)l, 16, 0, 0);
}

// counted-vmcnt sync points (T4): sched_barrier pins both sides so no
// LDS read can hoist above the barrier and no stage can sink below its
// phase (rules #18/#21). vmcnt(6) = exactly one staged tile (6 loads)
// may remain in flight across the barrier; oldest-first retire (m135)
// guarantees the tile about to be consumed has landed.
__device__ __forceinline__ void sync_vm6() {
    asm volatile("s_waitcnt vmcnt(6)" ::: "memory");
    __builtin_amdgcn_sched_barrier(0);
    __builtin_amdgcn_s_barrier();
    __builtin_amdgcn_sched_barrier(0);
}
__device__ __forceinline__ void sync_vm0() {
    asm volatile("s_waitcnt vmcnt(0)" ::: "memory");
    __builtin_amdgcn_sched_barrier(0);
    __builtin_amdgcn_s_barrier();
    __builtin_amdgcn_sched_barrier(0);
}

__global__ __launch_bounds__(256) void f32_to_bf16(const float* __restrict__ s,
                                                   short* __restrict__ d, int n4) {
    int i = blockIdx.x * blockDim.x + threadIdx.x;
    const int stride = gridDim.x * blockDim.x;
    for (; i < n4; i += stride) {
        float4 f = ((const float4*)s)[i];
        short4v v;
        v[0] = f2bf(f.x); v[1] = f2bf(f.y); v[2] = f2bf(f.z); v[3] = f2bf(f.w);
        ((short4v*)d)[i] = v;
    }
}

// convert two equal-size fp32 arrays -> bf16 in one launch (y selects)
__global__ __launch_bounds__(256) void cvt2(const float* __restrict__ s0,
                                            const float* __restrict__ s1,
                                            short* __restrict__ d0,
                                            short* __restrict__ d1, int n4) {
    const float* s = blockIdx.y ? s1 : s0;
    short* d = blockIdx.y ? d1 : d0;
    int i = blockIdx.x * blockDim.x + threadIdx.x;
    const int stride = gridDim.x * blockDim.x;
    for (; i < n4; i += stride) {
        float4 f = ((const float4*)s)[i];
        short4v v;
        v[0] = f2bf(f.x); v[1] = f2bf(f.y); v[2] = f2bf(f.z); v[3] = f2bf(f.w);
        ((short4v*)d)[i] = v;
    }
}

// convert three weight matrices -> bf16; y==0 (Wq) pre-scaled by SC so the
// Q projection GEMM needs no epilogue scale.
__global__ __launch_bounds__(256) void wcvt3(const float* __restrict__ a,
                                             const float* __restrict__ b,
                                             const float* __restrict__ c,
                                             short* __restrict__ dst, int n4) {
    const float* s = (blockIdx.y == 0) ? a : (blockIdx.y == 1) ? b : c;
    const float m = (blockIdx.y == 0) ? SC : 1.0f;
    short* d = dst + (size_t)blockIdx.y * (size_t)n4 * 4;
    int i = blockIdx.x * blockDim.x + threadIdx.x;
    const int stride = gridDim.x * blockDim.x;
    for (; i < n4; i += stride) {
        float4 f = ((const float4*)s)[i];
        short4v v;
        v[0] = f2bf(f.x * m); v[1] = f2bf(f.y * m);
        v[2] = f2bf(f.z * m); v[3] = f2bf(f.w * m);
        ((short4v*)d)[i] = v;
    }
}

// One compute phase: K-half KS of the current BK=64 tile. Each of 8 waves
// (4M x 2N) reads 4 A-frags + 4 B-frags (ds_read_b128, swizzled) and does
// 16 MFMA wrapped in setprio (T5).
template <int KS>
__device__ __forceinline__ void do_phase(const short* Ab, const short* Bb,
                                         floatx4 (&acc)[4][4], int wm, int wn,
                                         int lane16, int quad, int fsw) {
    short8 af[4], bf[4];
#pragma unroll
    for (int i = 0; i < 4; ++i)
        af[i] = *(const short8*)&Ab[KS * (256 * 32) + (wm + i * 16 + lane16) * 32 +
                                    ((quad ^ fsw) * 8)];
#pragma unroll
    for (int j = 0; j < 4; ++j)
        bf[j] = *(const short8*)&Bb[KS * (128 * 32) + (wn + j * 16 + lane16) * 32 +
                                    ((quad ^ fsw) * 8)];
    __builtin_amdgcn_s_setprio(1);
#pragma unroll
    for (int i = 0; i < 4; ++i)
#pragma unroll
        for (int j = 0; j < 4; ++j)
            acc[i][j] = __builtin_amdgcn_mfma_f32_16x16x32_bf16(af[i], bf[j],
                                                                acc[i][j], 0, 0, 0);
    __builtin_amdgcn_s_setprio(0);
}

// Y[m][n] = sum_k A[m][k] * B[n][k]  (NT GEMM, M=8192, N=K=1024). A,B bf16.
// BM=256 x BN=128, BK=64, 512 threads = 8 waves (4M x 2N), per-wave 64x64.
// TRIPLE-buffered LDS (144 KiB), 2-K-tile-deep prefetch: tile t+2 is staged
// at the top of iter t (right after the sync), giving ~2 K-tiles (~1400+
// cyc) of load cover -- round-4's single-phase cover (~600 cyc) left every
// sync stalled on L2 latency + per-CU L2 transfer with no cross-block TLP
// (1 block/CU). ONE barrier per K-tile, s_waitcnt vmcnt(6) (= one tile's
// loads outstanding); never drained to 0 until the tail.
// Buffer recycle: at iter t's barrier all waves finished reading tile t-1,
// so buf[(t+2)%3] == buf[(t-1)%3] is free to receive tile t+2.
// XOR-chunk swizzle with key (row>>1)&3 pre-applied to the per-lane GLOBAL
// address (global_load_lds lands linearly); reads de-swizzle with
// fsw=(lane16>>1)&3. OUT_MODE 0: bf16 row-major; 1: bf16 V-transposed
// [(b*16+h)*64+d][s]; 2: fp32 row-major (final output).
template <int OUT_MODE>
__device__ __forceinline__ void gemm_body(const short* A, const short* B,
                                          void* Yp) {
    __shared__ __align__(16) short Asw[3][2][256 * 32]; // [buf][ks][row*32+ch]
    __shared__ __align__(16) short Bsw[3][2][128 * 32];

    const int tid = threadIdx.x;
    const int w = tid >> 6, l = tid & 63;
    const int lane16 = l & 15, quad = l >> 4;
    const int wm = (w >> 1) * 64, wn = (w & 1) * 64;
    const int m0 = blockIdx.x * 256, n0 = blockIdx.y * 128;
    const int fsw = (lane16 >> 1) & 3; // fragment-read swizzle key

    // staging ownership: thread -> row rr (and rr+128 for A), 16B chunk cc,
    // pre-swizzled on the global side. Key (rr>>1)&3 == ((rr+128)>>1)&3.
    const int rr = tid >> 2;                    // 0..127
    const int cc = (tid & 3) ^ ((rr >> 1) & 3); // swizzled global chunk
    const int ldsW0 = (w * 16) * 32;            // wave's linear landing (shorts)
    const int ldsW1 = (128 + w * 16) * 32;

    auto stage = [&](int t) { // 6 VMEM instructions per wave
        const int k0 = t * 64, bufi = t % 3;
#pragma unroll
        for (int ks = 0; ks < 2; ++ks) {
            const short* ga = A + (size_t)(m0 + rr) * DMODEL + k0 + ks * 32 + cc * 8;
            ld16(ga, &Asw[bufi][ks][ldsW0]);
            ld16(ga + (size_t)128 * DMODEL, &Asw[bufi][ks][ldsW1]);
            const short* gb = B + (size_t)(n0 + rr) * DMODEL + k0 + ks * 32 + cc * 8;
            ld16(gb, &Bsw[bufi][ks][ldsW0]);
        }
    };

    floatx4 acc[4][4];
#pragma unroll
    for (int i = 0; i < 4; ++i)
#pragma unroll
        for (int j = 0; j < 4; ++j) acc[i][j] = {0.f, 0.f, 0.f, 0.f};

    constexpr int NT = DMODEL / 64; // 16 K-tiles
    // prologue: tiles 0 and 1 in flight (12 loads)
    stage(0);
    stage(1);

    for (int t = 0; t < NT; ++t) {
        // sync: tile t landed (outstanding <= tile t+1's 6 loads);
        // barrier: all waves done reading tile t-1.
        if (t + 1 < NT) sync_vm6(); else sync_vm0();
        if (t + 2 < NT) stage(t + 2); // into buf[(t+2)%3] == buf[(t-1)%3]
        const short* Ab = &Asw[t % 3][0][0];
        const short* Bb = &Bsw[t % 3][0][0];
        do_phase<0>(Ab, Bb, acc, wm, wn, lane16, quad, fsw);
        do_phase<1>(Ab, Bb, acc, wm, wn, lane16, quad, fsw);
    }

    const int gmb = m0 + wm, gnb = n0 + wn;
    if (OUT_MODE == 0) {
        short* Y = (short*)Yp;
#pragma unroll
        for (int mi = 0; mi < 4; ++mi)
#pragma unroll
            for (int ni = 0; ni < 4; ++ni) {
                const int gm = gmb + mi * 16 + quad * 4;
                const int gn = gnb + ni * 16 + lane16;
#pragma unroll
                for (int r = 0; r < 4; ++r)
                    Y[(size_t)(gm + r) * DMODEL + gn] = f2bf(acc[mi][ni][r]);
            }
    } else if (OUT_MODE == 1) {
        short* Y = (short*)Yp;
#pragma unroll
        for (int mi = 0; mi < 4; ++mi)
#pragma unroll
            for (int ni = 0; ni < 4; ++ni) {
                const int gm = gmb + mi * 16 + quad * 4;
                const int gn = gnb + ni * 16 + lane16;
                const int bb = gm >> 11, ss = gm & (SEQ - 1);
                const int hh = gn >> 6, dd = gn & 63;
                const size_t base = ((size_t)(bb * NHEADS + hh) * DKH + dd) * SEQ + ss;
                short4v vv;
#pragma unroll
                for (int r = 0; r < 4; ++r) vv[r] = f2bf(acc[mi][ni][r]);
                *(short4v*)(Y + base) = vv;
            }
    } else {
        float* Y = (float*)Yp;
#pragma unroll
        for (int mi = 0; mi < 4; ++mi)
#pragma unroll
            for (int ni = 0; ni < 4; ++ni) {
                const int gm = gmb + mi * 16 + quad * 4;
                const int gn = gnb + ni * 16 + lane16;
#pragma unroll
                for (int r = 0; r < 4; ++r)
                    Y[(size_t)(gm + r) * DMODEL + gn] = acc[mi][ni][r];
            }
    }
}

template <int OUT_MODE>
__global__ __launch_bounds__(512, 2) void gemm_nt(const short* __restrict__ A,
                                                  const short* __restrict__ B,
                                                  void* __restrict__ Yp) {
    gemm_body<OUT_MODE>(A, B, Yp);
}

// Q and K projections batched in one launch: grid (32, 8, 2), z selects.
// 512 blocks = two full-chip passes at 1 block/CU.
__global__ __launch_bounds__(512, 2) void gemm_qk(const short* __restrict__ Aq,
                                                  const short* __restrict__ Ak,
                                                  const short* __restrict__ Wqk,
                                                  short* __restrict__ Yq,
                                                  short* __restrict__ Yk) {
    const int z = blockIdx.z;
    gemm_body<0>(z ? Ak : Aq, Wqk + (size_t)z * WE, z ? Yk : Yq);
}

// Flash attention, causal, S^T form, no max-subtraction. (unchanged)
__global__ __launch_bounds__(256, 4) void attn_fwd(const short* __restrict__ Qb,
                                                   const short* __restrict__ Kb,
                                                   const short* __restrict__ Vt,
                                                   short* __restrict__ Oc) {
    __shared__ __align__(16) short Kl[2][64 * 64];
    __shared__ __align__(16) short Vl[2][64 * 64];
    __shared__ __align__(16) short Plds[4][16][64]; // per-wave P transpose, XOR-swizzled

    const int bh = blockIdx.x;                        // XCD = bh % 8
    const int qt = (int)(gridDim.y - 1) - blockIdx.y; // longest blocks first
    const int b = bh >> 4, h = bh & 15;
    const int tid = threadIdx.x;
    const int w = tid >> 6, l = tid & 63;
    const int lane16 = l & 15, quad = l >> 4;

    const short* Qrow =
        Qb + ((size_t)b * SEQ + qt * 64 + w * 16 + lane16) * DMODEL + h * DKH;
    const short8 qf0 = *(const short8*)(Qrow + quad * 8);
    const short8 qf1 = *(const short8*)(Qrow + 32 + quad * 8);

    const int r0 = tid >> 3, c0 = tid & 7;
    const int sc0 = c0 ^ (r0 & 7);
    const short* Kg = Kb + (size_t)b * SEQ * DMODEL + h * DKH; // K[s][d]
    const short* Vg = Vt + (size_t)bh * DKH * SEQ;             // V^T[d][s]

    short8 kra, krb, vra, vrb;
    kra = *(const short8*)(Kg + (size_t)r0 * DMODEL + c0 * 8);
    krb = *(const short8*)(Kg + (size_t)(r0 + 32) * DMODEL + c0 * 8);
    vra = *(const short8*)(Vg + (size_t)r0 * SEQ + c0 * 8);
    vrb = *(const short8*)(Vg + (size_t)(r0 + 32) * SEQ + c0 * 8);
    *(short8*)&Kl[0][r0 * 64 + sc0 * 8] = kra;
    *(short8*)&Kl[0][(r0 + 32) * 64 + sc0 * 8] = krb;
    *(short8*)&Vl[0][r0 * 64 + sc0 * 8] = vra;
    *(short8*)&Vl[0][(r0 + 32) * 64 + sc0 * 8] = vrb;
    if (qt > 0) {
        kra = *(const short8*)(Kg + (size_t)(64 + r0) * DMODEL + c0 * 8);
        krb = *(const short8*)(Kg + (size_t)(64 + r0 + 32) * DMODEL + c0 * 8);
        vra = *(const short8*)(Vg + (size_t)r0 * SEQ + 64 + c0 * 8);
        vrb = *(const short8*)(Vg + (size_t)(r0 + 32) * SEQ + 64 + c0 * 8);
    }

    floatx4 oacc[4];
#pragma unroll
    for (int ni = 0; ni < 4; ++ni) oacc[ni] = {0.f, 0.f, 0.f, 0.f};
    float Lp = 0.f;
    const int swz = lane16 & 7;
    const int psw = lane16 & 7;

    for (int kt = 0; kt <= qt; ++kt) {
        const int cur = kt & 1;
        __syncthreads();
        if (kt < qt) {
            const int nb = cur ^ 1;
            *(short8*)&Kl[nb][r0 * 64 + sc0 * 8] = kra;
            *(short8*)&Kl[nb][(r0 + 32) * 64 + sc0 * 8] = krb;
            *(short8*)&Vl[nb][r0 * 64 + sc0 * 8] = vra;
            *(short8*)&Vl[nb][(r0 + 32) * 64 + sc0 * 8] = vrb;
            if (kt + 1 < qt) {
                const int kn = (kt + 2) * 64;
                kra = *(const short8*)(Kg + (size_t)(kn + r0) * DMODEL + c0 * 8);
                krb = *(const short8*)(Kg + (size_t)(kn + r0 + 32) * DMODEL + c0 * 8);
                vra = *(const short8*)(Vg + (size_t)r0 * SEQ + kn + c0 * 8);
                vrb = *(const short8*)(Vg + (size_t)(r0 + 32) * SEQ + kn + c0 * 8);
            }
        }

        float p[4][4];
#pragma unroll
        for (int nt = 0; nt < 4; ++nt) {
            const short* kr = &Kl[cur][(nt * 16 + lane16) * 64];
            floatx4 st = {0.f, 0.f, 0.f, 0.f};
            st = __builtin_amdgcn_mfma_f32_16x16x32_bf16(
                *(const short8*)(kr + (quad ^ swz) * 8), qf0, st, 0, 0, 0);
            st = __builtin_amdgcn_mfma_f32_16x16x32_bf16(
                *(const short8*)(kr + ((4 + quad) ^ swz) * 8), qf1, st, 0, 0, 0);
#pragma unroll
            for (int r = 0; r < 4; ++r) p[nt][r] = st[r];
        }

#pragma unroll
        for (int nt = 0; nt < 4; ++nt)
#pragma unroll
            for (int r = 0; r < 4; ++r) p[nt][r] = __builtin_amdgcn_exp2f(p[nt][r]);

        if (kt == qt) {
            const int qloc = w * 16 + lane16;
#pragma unroll
            for (int nt = 0; nt < 4; ++nt)
#pragma unroll
                for (int r = 0; r < 4; ++r)
                    if (nt * 16 + quad * 4 + r > qloc) p[nt][r] = 0.f;
        }

        float rs01 = 0.f, rs23 = 0.f;
#pragma unroll
        for (int nt = 0; nt < 4; ++nt)
#pragma unroll
            for (int r = 0; r < 4; ++r) {
                if (nt < 2) rs01 += p[nt][r]; else rs23 += p[nt][r];
            }
        Lp += rs01 + rs23;

#pragma unroll
        for (int nt = 0; nt < 4; ++nt) {
            const short2 lo = pk2(p[nt][0], p[nt][1]);
            const short2 hi = pk2(p[nt][2], p[nt][3]);
            short4v pk;
            pk[0] = lo.x; pk[1] = lo.y; pk[2] = hi.x; pk[3] = hi.y;
            const int pch = (nt * 2 + (quad >> 1)) ^ psw;
            *(short4v*)&Plds[w][lane16][pch * 8 + (quad & 1) * 4] = pk;
        }
        const short8 pf0 = *(const short8*)&Plds[w][lane16][(quad ^ psw) * 8];
        const short8 pf1 = *(const short8*)&Plds[w][lane16][((4 + quad) ^ psw) * 8];

#pragma unroll
        for (int ni = 0; ni < 4; ++ni) {
            const short* vr = &Vl[cur][(ni * 16 + lane16) * 64];
            oacc[ni] = __builtin_amdgcn_mfma_f32_16x16x32_bf16(
                pf0, *(const short8*)(vr + (quad ^ swz) * 8), oacc[ni], 0, 0, 0);
            oacc[ni] = __builtin_amdgcn_mfma_f32_16x16x32_bf16(
                pf1, *(const short8*)(vr + ((4 + quad) ^ swz) * 8), oacc[ni], 0, 0, 0);
        }
    }

    float L = Lp + __shfl_xor(Lp, 16);
    L += __shfl_xor(L, 32);
    float linv[4];
#pragma unroll
    for (int r = 0; r < 4; ++r) linv[r] = 1.f / __shfl(L, quad * 4 + r);
#pragma unroll
    for (int r = 0; r < 4; ++r) {
        const int qg = qt * 64 + w * 16 + quad * 4 + r;
#pragma unroll
        for (int ni = 0; ni < 4; ++ni)
            Oc[((size_t)b * SEQ + qg) * DMODEL + h * DKH + ni * 16 + lane16] =
                f2bf(oacc[ni][r] * linv[r]);
    }
}

extern "C" void kernel_launch(void* const* d_in, const int* in_sizes, int n_in,
                              void* d_out, int out_size, void* d_ws, size_t ws_size,
                              hipStream_t stream) {
    const float* q = (const float*)d_in[0];
    const float* k = (const float*)d_in[1];
    const float* v = (const float*)d_in[2];
    const float* Wq = (const float*)d_in[3];
    const float* Wk = (const float*)d_in[4];
    const float* Wv = (const float*)d_in[5];
    const float* Wo = (const float*)d_in[6];

    short* Qb = (short*)d_ws;     // ws: exactly 4*NE bf16 = 67.1 MB
    short* Kb = Qb + NE;
    short* Vt = Kb + NE;
    short* Cc = Vt + NE;
    // scratch inside d_out (33.5 MB fp32, dead until the final GEMM):
    short* Wqb = (short*)d_out;   // [0, 3*WE): bf16 Wq (SC-scaled) / Wk / Wv
    short* Wkb = Wqb + WE;
    short* Wvb = Wqb + 2 * WE;
    short* Kbf = Wqb + 3 * WE;    // [3*WE, 3*WE+NE): bf16 key activation
    short* Wob = Vt;              // Vt dead after attn

    dim3 gg(MROWS / 256, DMODEL / 128);     // (32, 8): 256 blocks = 1/CU
    dim3 gqk(MROWS / 256, DMODEL / 128, 2); // (32, 8, 2): 512 blocks
    dim3 ga(BATCH * NHEADS, SEQ / 64);      // (64, 32): x = bh -> XCD affinity
    const int actN4 = (int)(NE / 4), wN4 = (int)(WE / 4);

    wcvt3<<<dim3(256, 3), 256, 0, stream>>>(Wq, Wk, Wv, (short*)d_out, wN4);
    cvt2<<<dim3(1024, 2), 256, 0, stream>>>(q, k, Cc, Kbf, actN4);
    gemm_qk<<<gqk, 512, 0, stream>>>(Cc, Kbf, Wqb, Qb, Kb);
    f32_to_bf16<<<2048, 256, 0, stream>>>(v, Cc, actN4);
    gemm_nt<1><<<gg, 512, 0, stream>>>(Cc, Wvb, Vt);
    attn_fwd<<<ga, 256, 0, stream>>>(Qb, Kb, Vt, Cc);
    f32_to_bf16<<<512, 256, 0, stream>>>(Wo, Wob, wN4);
    gemm_nt<2><<<gg, 512, 0, stream>>>(Cc, Wob, d_out);
}

// Round 6
// 306.319 us; speedup vs baseline: 1.0741x; 1.0497x over previous
//
#include <hip/hip_runtime.h>
#include <hip/hip_bf16.h>

typedef short short8 __attribute__((ext_vector_type(8)));
typedef short short4v __attribute__((ext_vector_type(4)));
typedef float floatx4 __attribute__((ext_vector_type(4)));

constexpr int BATCH = 4;
constexpr int SEQ = 2048;
constexpr int DMODEL = 1024;
constexpr int NHEADS = 16;
constexpr int DKH = 64;
constexpr int MROWS = BATCH * SEQ;             // 8192
constexpr size_t NE = (size_t)MROWS * DMODEL;  // 8388608 elements
constexpr size_t WE = (size_t)DMODEL * DMODEL; // 1048576 elements
constexpr float SC = 0.18033688011112042f;     // (1/8) * log2(e), folded into Wq

__device__ __forceinline__ short f2bf(float f) {
    unsigned u = __float_as_uint(f);
    u += 0x7fffu + ((u >> 16) & 1u);
    return (short)(u >> 16);
}

__device__ __forceinline__ short2 pk2(float a, float b) {
    __hip_bfloat162 h = __float22bfloat162_rn(float2{a, b});
    short2 r;
    __builtin_memcpy(&r, &h, 4);
    return r;
}

// async 16B global -> LDS (lds dst is wave-uniform; HW adds lane*16)
__device__ __forceinline__ void ld16(const void* g, void* l) {
    __builtin_amdgcn_global_load_lds(
        (const __attribute__((address_space(1))) unsigned int*)g,
        (__attribute__((address_space(3))) unsigned int*)l, 16, 0, 0);
}

__global__ __launch_bounds__(256) void f32_to_bf16(const float* __restrict__ s,
                                                   short* __restrict__ d, int n4) {
    int i = blockIdx.x * blockDim.x + threadIdx.x;
    const int stride = gridDim.x * blockDim.x;
    for (; i < n4; i += stride) {
        float4 f = ((const float4*)s)[i];
        short4v v;
        v[0] = f2bf(f.x); v[1] = f2bf(f.y); v[2] = f2bf(f.z); v[3] = f2bf(f.w);
        ((short4v*)d)[i] = v;
    }
}

// convert two equal-size fp32 arrays -> bf16 in one launch (y selects)
__global__ __launch_bounds__(256) void cvt2(const float* __restrict__ s0,
                                            const float* __restrict__ s1,
                                            short* __restrict__ d0,
                                            short* __restrict__ d1, int n4) {
    const float* s = blockIdx.y ? s1 : s0;
    short* d = blockIdx.y ? d1 : d0;
    int i = blockIdx.x * blockDim.x + threadIdx.x;
    const int stride = gridDim.x * blockDim.x;
    for (; i < n4; i += stride) {
        float4 f = ((const float4*)s)[i];
        short4v v;
        v[0] = f2bf(f.x); v[1] = f2bf(f.y); v[2] = f2bf(f.z); v[3] = f2bf(f.w);
        ((short4v*)d)[i] = v;
    }
}

// convert three weight matrices -> bf16; y==0 (Wq) pre-scaled by SC so the
// Q projection GEMM needs no epilogue scale.
__global__ __launch_bounds__(256) void wcvt3(const float* __restrict__ a,
                                             const float* __restrict__ b,
                                             const float* __restrict__ c,
                                             short* __restrict__ dst, int n4) {
    const float* s = (blockIdx.y == 0) ? a : (blockIdx.y == 1) ? b : c;
    const float m = (blockIdx.y == 0) ? SC : 1.0f;
    short* d = dst + (size_t)blockIdx.y * (size_t)n4 * 4;
    int i = blockIdx.x * blockDim.x + threadIdx.x;
    const int stride = gridDim.x * blockDim.x;
    for (; i < n4; i += stride) {
        float4 f = ((const float4*)s)[i];
        short4v v;
        v[0] = f2bf(f.x * m); v[1] = f2bf(f.y * m);
        v[2] = f2bf(f.z * m); v[3] = f2bf(f.w * m);
        ((short4v*)d)[i] = v;
    }
}

// Y[m][n] = sum_k A[m][k] * B[n][k]  (NT GEMM, M=8192, N=K=1024). A,B bf16.
// ROUND-2 structure (best measured ensemble): 128x128 tile, 256 threads,
// 2-phase double-buffered: stage tile t+1 (async global_load_lds) BEFORE
// the ds_read+MFMA of tile t; ONE barrier per iter. Rounds 3-5's deeper
// 256-wide pipelines were all neutral-to-negative vs this.
// OUT_MODE 0: bf16 row-major; 1: bf16 V-transposed [(b*16+h)*64+d][s];
// 2: fp32 row-major (final output).
template <int OUT_MODE>
__device__ __forceinline__ void gemm_body(const short* __restrict__ A,
                                          const short* __restrict__ B,
                                          void* __restrict__ Yp) {
    // swizzled, unpadded (global_load_lds needs lane-ordered contiguity):
    // Xsw[row][ch] (ch = 8-bf16 chunk) holds X[row][ch ^ ((row>>1)&3)]
    __shared__ __align__(16) short Asw[2][128 * 32];
    __shared__ __align__(16) short Bsw[2][128 * 32];

    const int tid = threadIdx.x;
    const int w = tid >> 6, l = tid & 63;
    const int lane16 = l & 15, quad = l >> 4;
    const int wm = (w >> 1) * 64, wn = (w & 1) * 64;
    const int m0 = blockIdx.x * 128, n0 = blockIdx.y * 128;
    const int fsw = (lane16 >> 1) & 3; // fragment-read swizzle

    auto stage = [&](int k0, int bufi) {
#pragma unroll
        for (int i = 0; i < 2; ++i) {
            const int id = i * 256 + tid;
            const int row = id >> 2, ch = id & 3;
            const int sch = ch ^ ((row >> 1) & 3);
            ld16(A + (size_t)(m0 + row) * DMODEL + k0 + sch * 8,
                 &Asw[bufi][(i * 256 + w * 64) * 8]);
            ld16(B + (size_t)(n0 + row) * DMODEL + k0 + sch * 8,
                 &Bsw[bufi][(i * 256 + w * 64) * 8]);
        }
    };

    floatx4 acc[4][4];
#pragma unroll
    for (int i = 0; i < 4; ++i)
#pragma unroll
        for (int j = 0; j < 4; ++j) acc[i][j] = {0.f, 0.f, 0.f, 0.f};

    constexpr int NT = DMODEL / 32; // 32 K-tiles
    stage(0, 0);
    __syncthreads(); // tile 0 landed (barrier drains vmcnt)

    for (int t = 0; t < NT; ++t) {
        const int cur = t & 1;
        if (t + 1 < NT) stage((t + 1) * 32, cur ^ 1); // async, in flight during MFMA

        short8 af[4], bfr[4];
#pragma unroll
        for (int mi = 0; mi < 4; ++mi)
            af[mi] = *(const short8*)(&Asw[cur][(wm + mi * 16 + lane16) * 32 +
                                                ((quad ^ fsw) * 8)]);
#pragma unroll
        for (int ni = 0; ni < 4; ++ni)
            bfr[ni] = *(const short8*)(&Bsw[cur][(wn + ni * 16 + lane16) * 32 +
                                                 ((quad ^ fsw) * 8)]);
#pragma unroll
        for (int mi = 0; mi < 4; ++mi)
#pragma unroll
            for (int ni = 0; ni < 4; ++ni)
                acc[mi][ni] = __builtin_amdgcn_mfma_f32_16x16x32_bf16(af[mi], bfr[ni],
                                                                      acc[mi][ni], 0, 0, 0);
        __syncthreads(); // waves done reading buf[cur]; tile t+1 loads drained
    }

    const int gmb = m0 + wm, gnb = n0 + wn;
    if (OUT_MODE == 0) {
        short* Y = (short*)Yp;
#pragma unroll
        for (int mi = 0; mi < 4; ++mi)
#pragma unroll
            for (int ni = 0; ni < 4; ++ni) {
                const int gm = gmb + mi * 16 + quad * 4;
                const int gn = gnb + ni * 16 + lane16;
#pragma unroll
                for (int r = 0; r < 4; ++r)
                    Y[(size_t)(gm + r) * DMODEL + gn] = f2bf(acc[mi][ni][r]);
            }
    } else if (OUT_MODE == 1) {
        short* Y = (short*)Yp;
#pragma unroll
        for (int mi = 0; mi < 4; ++mi)
#pragma unroll
            for (int ni = 0; ni < 4; ++ni) {
                const int gm = gmb + mi * 16 + quad * 4;
                const int gn = gnb + ni * 16 + lane16;
                const int bb = gm >> 11, ss = gm & (SEQ - 1);
                const int hh = gn >> 6, dd = gn & 63;
                const size_t base = ((size_t)(bb * NHEADS + hh) * DKH + dd) * SEQ + ss;
                short4v vv;
#pragma unroll
                for (int r = 0; r < 4; ++r) vv[r] = f2bf(acc[mi][ni][r]);
                *(short4v*)(Y + base) = vv;
            }
    } else {
        float* Y = (float*)Yp;
#pragma unroll
        for (int mi = 0; mi < 4; ++mi)
#pragma unroll
            for (int ni = 0; ni < 4; ++ni) {
                const int gm = gmb + mi * 16 + quad * 4;
                const int gn = gnb + ni * 16 + lane16;
#pragma unroll
                for (int r = 0; r < 4; ++r)
                    Y[(size_t)(gm + r) * DMODEL + gn] = acc[mi][ni][r];
            }
    }
}

template <int OUT_MODE>
__global__ __launch_bounds__(256, 3) void gemm_nt(const short* __restrict__ A,
                                                  const short* __restrict__ B,
                                                  void* __restrict__ Yp) {
    gemm_body<OUT_MODE>(A, B, Yp);
}

// Q and K projections batched in one launch: grid (64, 8, 2), z selects.
__global__ __launch_bounds__(256, 3) void gemm_qk(const short* __restrict__ Aq,
                                                  const short* __restrict__ Ak,
                                                  const short* __restrict__ Wqk,
                                                  short* __restrict__ Yq,
                                                  short* __restrict__ Yk) {
    const int z = blockIdx.z;
    gemm_body<0>(z ? Ak : Aq, Wqk + (size_t)z * WE, z ? Yk : Yq);
}

// Flash attention, causal, S^T form, no max-subtraction.
// QBLK=128: 512 threads / 8 waves per block, each wave owns 16 Q-rows.
// K/V tiles 64x64 double-buffered (reg-prefetch one tile ahead): per unit
// of output, global loads / LDS writes / barriers all HALVE vs QBLK=64.
// LDS 48 KiB -> 3 blocks/CU = 24 waves/CU (75% cap, was 50%).
// Waves 0-3 hit their diagonal at kt=2qt and skip the last tile (uniform
// continue; barrier stays at loop top so counts match).
// XOR-swizzled unpadded LDS rows; Plds [8][16][64] swizzled.
// XCD-affine grid (x = bh). Q pre-scaled by (1/8)*log2(e) via Wq;
// Vt is [(b*16+h)*64+d][s].
__global__ __launch_bounds__(512, 6) void attn_fwd(const short* __restrict__ Qb,
                                                   const short* __restrict__ Kb,
                                                   const short* __restrict__ Vt,
                                                   short* __restrict__ Oc) {
    __shared__ __align__(16) short Kl[2][64 * 64];
    __shared__ __align__(16) short Vl[2][64 * 64];
    __shared__ __align__(16) short Plds[8][16][64]; // per-wave P transpose, XOR-swizzled

    const int bh = blockIdx.x;                        // XCD = bh % 8
    const int qt = (int)(gridDim.y - 1) - blockIdx.y; // longest blocks first; 0..15
    const int b = bh >> 4, h = bh & 15;
    const int tid = threadIdx.x;
    const int w = tid >> 6, l = tid & 63;
    const int lane16 = l & 15, quad = l >> 4;

    // Q fragment (B-operand: n=q=lane16 over k=d); pre-scaled in projection
    const short* Qrow =
        Qb + ((size_t)b * SEQ + qt * 128 + w * 16 + lane16) * DMODEL + h * DKH;
    const short8 qf0 = *(const short8*)(Qrow + quad * 8);
    const short8 qf1 = *(const short8*)(Qrow + 32 + quad * 8);

    // staging ownership (512 threads cover one 64x64 tile of K and of V):
    // row r0 = tid>>3 (0..63), logical 16B chunk c0 = tid&7,
    // stored at physical chunk c0 ^ (r0&7)
    const int r0 = tid >> 3, c0 = tid & 7;
    const int sc0 = c0 ^ (r0 & 7);
    const short* Kg = Kb + (size_t)b * SEQ * DMODEL + h * DKH; // K[s][d]
    const short* Vg = Vt + (size_t)bh * DKH * SEQ;             // V^T[d][s]

    const int ktmax = 2 * qt + 1; // always >= 1 (block covers 128 q-rows)
    short8 kra, vra;
    // prologue: tile 0 -> regs -> buf 0; tile 1 -> regs
    kra = *(const short8*)(Kg + (size_t)r0 * DMODEL + c0 * 8);
    vra = *(const short8*)(Vg + (size_t)r0 * SEQ + c0 * 8);
    *(short8*)&Kl[0][r0 * 64 + sc0 * 8] = kra;
    *(short8*)&Vl[0][r0 * 64 + sc0 * 8] = vra;
    kra = *(const short8*)(Kg + (size_t)(64 + r0) * DMODEL + c0 * 8);
    vra = *(const short8*)(Vg + (size_t)r0 * SEQ + 64 + c0 * 8);

    floatx4 oacc[4];
#pragma unroll
    for (int ni = 0; ni < 4; ++ni) oacc[ni] = {0.f, 0.f, 0.f, 0.f};
    float Lp = 0.f;
    const int swz = lane16 & 7;
    const int psw = lane16 & 7;        // Plds chunk-swizzle key (per-row)
    const int dkt = 2 * qt + (w >> 2); // this wave's diagonal tile index
    const int qloc = (w * 16 + lane16) & 63;

    for (int kt = 0; kt <= ktmax; ++kt) {
        const int cur = kt & 1;
        __syncthreads(); // tile kt's buf writes (iter kt-1 / prologue) visible;
                         // all waves done reading buf[(kt+1)&1] (tile kt-1)
        if (kt < ktmax) { // stash prefetched tile kt+1 into the other buffer
            const int nb = cur ^ 1;
            *(short8*)&Kl[nb][r0 * 64 + sc0 * 8] = kra;
            *(short8*)&Vl[nb][r0 * 64 + sc0 * 8] = vra;
            if (kt + 1 < ktmax) { // prefetch tile kt+2 -> regs
                const int kn = (kt + 2) * 64;
                kra = *(const short8*)(Kg + (size_t)(kn + r0) * DMODEL + c0 * 8);
                vra = *(const short8*)(Vg + (size_t)r0 * SEQ + kn + c0 * 8);
            }
        }
        if (kt > dkt) continue; // waves 0-3 skip the final tile (wave-uniform)

        // S^T = K·Q^T: p[nt][r] = S^T[key=nt*16+quad*4+r][q=lane16] (log2 dom)
        float p[4][4];
#pragma unroll
        for (int nt = 0; nt < 4; ++nt) {
            const short* kr = &Kl[cur][(nt * 16 + lane16) * 64];
            floatx4 st = {0.f, 0.f, 0.f, 0.f};
            st = __builtin_amdgcn_mfma_f32_16x16x32_bf16(
                *(const short8*)(kr + (quad ^ swz) * 8), qf0, st, 0, 0, 0);
            st = __builtin_amdgcn_mfma_f32_16x16x32_bf16(
                *(const short8*)(kr + ((4 + quad) ^ swz) * 8), qf1, st, 0, 0, 0);
#pragma unroll
            for (int r = 0; r < 4; ++r) p[nt][r] = st[r];
        }

        // exp2 (bounded scores: no max needed)
#pragma unroll
        for (int nt = 0; nt < 4; ++nt)
#pragma unroll
            for (int r = 0; r < 4; ++r) p[nt][r] = __builtin_amdgcn_exp2f(p[nt][r]);

        // causal zeroing: wave-uniform branch, diagonal tile only
        if (kt == dkt) {
#pragma unroll
            for (int nt = 0; nt < 4; ++nt)
#pragma unroll
                for (int r = 0; r < 4; ++r)
                    if (nt * 16 + quad * 4 + r > qloc) p[nt][r] = 0.f;
        }

        float rs01 = 0.f, rs23 = 0.f;
#pragma unroll
        for (int nt = 0; nt < 4; ++nt)
#pragma unroll
            for (int r = 0; r < 4; ++r) {
                if (nt < 2) rs01 += p[nt][r]; else rs23 += p[nt][r];
            }
        Lp += rs01 + rs23;

        // P (S^T C-layout) -> per-wave LDS -> A-operand layout (no barrier)
#pragma unroll
        for (int nt = 0; nt < 4; ++nt) {
            const short2 lo = pk2(p[nt][0], p[nt][1]);
            const short2 hi = pk2(p[nt][2], p[nt][3]);
            short4v pk;
            pk[0] = lo.x; pk[1] = lo.y; pk[2] = hi.x; pk[3] = hi.y;
            const int pch = (nt * 2 + (quad >> 1)) ^ psw;
            *(short4v*)&Plds[w][lane16][pch * 8 + (quad & 1) * 4] = pk;
        }
        const short8 pf0 = *(const short8*)&Plds[w][lane16][(quad ^ psw) * 8];
        const short8 pf1 = *(const short8*)&Plds[w][lane16][((4 + quad) ^ psw) * 8];

        // O += P·V (normalization deferred to epilogue)
#pragma unroll
        for (int ni = 0; ni < 4; ++ni) {
            const short* vr = &Vl[cur][(ni * 16 + lane16) * 64];
            oacc[ni] = __builtin_amdgcn_mfma_f32_16x16x32_bf16(
                pf0, *(const short8*)(vr + (quad ^ swz) * 8), oacc[ni], 0, 0, 0);
            oacc[ni] = __builtin_amdgcn_mfma_f32_16x16x32_bf16(
                pf1, *(const short8*)(vr + ((4 + quad) ^ swz) * 8), oacc[ni], 0, 0, 0);
        }
    }

    // final L reduction (q = lane16 spread over 4 quads) + normalize + write
    float L = Lp + __shfl_xor(Lp, 16);
    L += __shfl_xor(L, 32);
    float linv[4];
#pragma unroll
    for (int r = 0; r < 4; ++r) linv[r] = 1.f / __shfl(L, quad * 4 + r);
#pragma unroll
    for (int r = 0; r < 4; ++r) {
        const int qg = qt * 128 + w * 16 + quad * 4 + r;
#pragma unroll
        for (int ni = 0; ni < 4; ++ni)
            Oc[((size_t)b * SEQ + qg) * DMODEL + h * DKH + ni * 16 + lane16] =
                f2bf(oacc[ni][r] * linv[r]);
    }
}

extern "C" void kernel_launch(void* const* d_in, const int* in_sizes, int n_in,
                              void* d_out, int out_size, void* d_ws, size_t ws_size,
                              hipStream_t stream) {
    const float* q = (const float*)d_in[0];
    const float* k = (const float*)d_in[1];
    const float* v = (const float*)d_in[2];
    const float* Wq = (const float*)d_in[3];
    const float* Wk = (const float*)d_in[4];
    const float* Wv = (const float*)d_in[5];
    const float* Wo = (const float*)d_in[6];

    short* Qb = (short*)d_ws;     // ws: exactly 4*NE bf16 = 67.1 MB
    short* Kb = Qb + NE;
    short* Vt = Kb + NE;
    short* Cc = Vt + NE;
    // scratch inside d_out (33.5 MB fp32, dead until the final GEMM):
    short* Wqb = (short*)d_out;   // [0, 3*WE): bf16 Wq (SC-scaled) / Wk / Wv
    short* Wkb = Wqb + WE;
    short* Wvb = Wqb + 2 * WE;
    short* Kbf = Wqb + 3 * WE;    // [3*WE, 3*WE+NE): bf16 key activation
    short* Wob = Vt;              // Vt dead after attn

    dim3 gg(MROWS / 128, DMODEL / 128);     // (64, 8): 512 blocks
    dim3 gqk(MROWS / 128, DMODEL / 128, 2); // (64, 8, 2): 1024 blocks
    dim3 ga(BATCH * NHEADS, SEQ / 128);     // (64, 16): x = bh -> XCD affinity
    const int actN4 = (int)(NE / 4), wN4 = (int)(WE / 4);

    wcvt3<<<dim3(256, 3), 256, 0, stream>>>(Wq, Wk, Wv, (short*)d_out, wN4);
    cvt2<<<dim3(1024, 2), 256, 0, stream>>>(q, k, Cc, Kbf, actN4);
    gemm_qk<<<gqk, 256, 0, stream>>>(Cc, Kbf, Wqb, Qb, Kb);
    f32_to_bf16<<<2048, 256, 0, stream>>>(v, Cc, actN4);
    gemm_nt<1><<<gg, 256, 0, stream>>>(Cc, Wvb, Vt);
    attn_fwd<<<ga, 512, 0, stream>>>(Qb, Kb, Vt, Cc);
    f32_to_bf16<<<512, 256, 0, stream>>>(Wo, Wob, wN4);
    gemm_nt<2><<<gg, 256, 0, stream>>>(Cc, Wob, d_out);
}